// Round 1
// baseline (480.433 us; speedup 1.0000x reference)
//
#include <hip/hip_runtime.h>
#include <stdint.h>

// RegimePatternBank:  B=32768 regime rows (D=512), P=4096 prototypes.
// out[b][16] = sum_k softmax(5*top3_cos_sims)_k * MLP([regime_b ; proto_topk])
//
// Strategy:
//  prep (x2): row norms, fp32-normalized protos, bf16-normalized rows (MFMA
//             inputs), and MLP projections rproj=W1[:, :512]@regime,
//             cproj=W1[:,512:]@proto (MLP layer-1 is linear in the concat).
//  topk:      bf16 MFMA GEMM sims = regimeN @ protoN^T (137 GFLOP) fused with
//             per-row top-8 selection (packed value|col keys). bf16 rounding
//             (~1e-4) << top-8 exclusion margin (~1.5e-2) => top-8 contains
//             the true fp32 top-3 w.h.p.
//  finalize:  fp64 rescore of the 8 candidates on fp32-normalized inputs,
//             exact top-3 (tie -> lower index), softmax, tiny MLP, weighted sum.

#define BDIM 512
#define NB   32768
#define NP   4096

typedef float  f32x4 __attribute__((ext_vector_type(4)));
typedef short  s16x8 __attribute__((ext_vector_type(8)));
typedef unsigned short u16;

__device__ __forceinline__ u16 f2bf(float f) {
  uint32_t u = __float_as_uint(f);
  return (u16)((u + 0x7FFFu + ((u >> 16) & 1u)) >> 16);
}
// monotone map: bf16 bits -> uint16 with float ordering (handles negatives)
__device__ __forceinline__ uint32_t mapbf(uint32_t h) {
  return h ^ ((h & 0x8000u) ? 0xFFFFu : 0x8000u);
}
__device__ __forceinline__ uint32_t umx(uint32_t a, uint32_t b) { return a > b ? a : b; }
__device__ __forceinline__ uint32_t umn(uint32_t a, uint32_t b) { return a > b ? b : a; }

// insert key into sorted-descending 8-list (bubble; 8x max/min)
__device__ __forceinline__ void ins8(uint32_t* t, uint32_t k) {
#pragma unroll
  for (int i = 0; i < 8; ++i) {
    uint32_t mx = umx(t[i], k), mn = umn(t[i], k);
    t[i] = mx; k = mn;
  }
}

// a,b sorted desc -> a = top-8 of union, sorted desc (bitonic merge network)
__device__ __forceinline__ void bmerge(uint32_t* a, const uint32_t* b) {
  uint32_t t[8];
#pragma unroll
  for (int i = 0; i < 8; ++i) t[i] = umx(a[i], b[7 - i]);   // bitonic top-8
#pragma unroll
  for (int i = 0; i < 4; ++i) { uint32_t x = umx(t[i], t[i + 4]), y = umn(t[i], t[i + 4]); t[i] = x; t[i + 4] = y; }
#pragma unroll
  for (int g = 0; g < 8; g += 4)
#pragma unroll
    for (int i = 0; i < 2; ++i) { uint32_t x = umx(t[g + i], t[g + i + 2]), y = umn(t[g + i], t[g + i + 2]); t[g + i] = x; t[g + i + 2] = y; }
#pragma unroll
  for (int p = 0; p < 8; p += 2) { uint32_t x = umx(t[p], t[p + 1]), y = umn(t[p], t[p + 1]); t[p] = x; t[p + 1] = y; }
#pragma unroll
  for (int i = 0; i < 8; ++i) a[i] = t[i];
}

__device__ __forceinline__ void mergeshfl(uint32_t* a, int mask) {
  uint32_t b[8];
#pragma unroll
  for (int i = 0; i < 8; ++i) b[i] = (uint32_t)__shfl_xor((int)a[i], mask, 64);
  bmerge(a, b);
}

// ---------------------------------------------------------------------------
// prep: 16 rows/block. Outputs: norm (max(|x|,eps)), bf16 normalized row,
// proj = W1[:, w1_off:w1_off+512] @ raw_row, optional fp32 normalized row.
// ---------------------------------------------------------------------------
__global__ __launch_bounds__(256) void prep_kernel(
    const float* __restrict__ src, const float* __restrict__ W1, int w1_off,
    u16* __restrict__ obf, float* __restrict__ onrm, float* __restrict__ oproj,
    float* __restrict__ onf32 /* may be null */)
{
  __shared__ float rows[16][512];
  __shared__ float scratch[8][32];
  const int t = threadIdx.x, l = t & 63, w = t >> 6;
  const long rowbase = (long)blockIdx.x * 16;

  { // stage 16 raw rows
    const int r = t >> 4, c0 = (t & 15) * 32;
    const float4* gp = (const float4*)(src + (rowbase + r) * BDIM + c0);
    float4* dp = (float4*)&rows[r][c0];
#pragma unroll
    for (int i = 0; i < 8; ++i) dp[i] = gp[i];
  }
  float wreg[64]; // thread (h=t&31, seg=t>>5) holds W1[h][w1_off+seg*64 .. +64)
  {
    const int h = t & 31, seg = t >> 5;
    const float* wp = W1 + h * 1024 + w1_off + seg * 64;
#pragma unroll
    for (int i = 0; i < 64; ++i) wreg[i] = wp[i];
  }
  __syncthreads();

  // normalize: wave w handles rows 4w..4w+3
#pragma unroll
  for (int i = 0; i < 4; ++i) {
    const int r = w * 4 + i;
    float4 a = *(const float4*)&rows[r][4 * l];
    float4 c = *(const float4*)&rows[r][256 + 4 * l];
    float ss = a.x * a.x + a.y * a.y + a.z * a.z + a.w * a.w
             + c.x * c.x + c.y * c.y + c.z * c.z + c.w * c.w;
#pragma unroll
    for (int msk = 1; msk < 64; msk <<= 1) ss += __shfl_xor(ss, msk, 64);
    const float n = fmaxf(sqrtf(ss), 1e-12f);
    if (l == 0) onrm[rowbase + r] = n;
    float4 qa, qc;
    qa.x = a.x / n; qa.y = a.y / n; qa.z = a.z / n; qa.w = a.w / n;
    qc.x = c.x / n; qc.y = c.y / n; qc.z = c.z / n; qc.w = c.w / n;
    ushort4 u0, u1;
    u0.x = f2bf(qa.x); u0.y = f2bf(qa.y); u0.z = f2bf(qa.z); u0.w = f2bf(qa.w);
    u1.x = f2bf(qc.x); u1.y = f2bf(qc.y); u1.z = f2bf(qc.z); u1.w = f2bf(qc.w);
    *(ushort4*)(obf + (rowbase + r) * BDIM + 4 * l) = u0;
    *(ushort4*)(obf + (rowbase + r) * BDIM + 256 + 4 * l) = u1;
    if (onf32) {
      *(float4*)(onf32 + (rowbase + r) * BDIM + 4 * l) = qa;
      *(float4*)(onf32 + (rowbase + r) * BDIM + 256 + 4 * l) = qc;
    }
  }

  // proj on RAW rows (MLP consumes raw regime/proto values)
  const int h = t & 31, seg = t >> 5;
  for (int r = 0; r < 16; ++r) {
    float p = 0.f;
#pragma unroll
    for (int i = 0; i < 16; ++i) {
      const float4 rv = *(const float4*)&rows[r][seg * 64 + 4 * i];
      p = fmaf(wreg[4 * i + 0], rv.x, p);
      p = fmaf(wreg[4 * i + 1], rv.y, p);
      p = fmaf(wreg[4 * i + 2], rv.z, p);
      p = fmaf(wreg[4 * i + 3], rv.w, p);
    }
    scratch[seg][h] = p;
    __syncthreads();
    if (t < 32) {
      float s2 = 0.f;
#pragma unroll
      for (int sg = 0; sg < 8; ++sg) s2 += scratch[sg][t];
      oproj[(rowbase + r) * 32 + t] = s2;
    }
    __syncthreads();
  }
}

// ---------------------------------------------------------------------------
// topk: block = 512 thr = 8 waves (2 wm x 4 wn). Block tile 128 rows x 512
// cols per n-iter (8 iters over P=4096), K staged in 32-wide LDS tiles.
// Wave tile 64x128: 4 M-frags x 8 N-frags of 16x16x32 bf16 MFMA.
// LDS layout [k-chunk][row] (16B units) -> conflict-free ds_read_b128 frags.
// Fused per-row running top-8 of packed keys (mapped bf16 value << 16 | col).
// ---------------------------------------------------------------------------
__global__ __launch_bounds__(512, 2) void topk_kernel(
    const u16* __restrict__ An,   // [32768][512] bf16 normalized regime
    const u16* __restrict__ Bn,   // [4096][512]  bf16 normalized protos
    int* __restrict__ top8out)    // [32768][8]
{
  __shared__ uint4 smem[3648];                 // 58368 B
  uint4* As = smem;                            // [4][128] 16B units, 8 KB
  uint4* Bs = smem + 512;                      // [4][512] 16B units, 32 KB
  u16*   dmp = (u16*)(smem + 2560);            // 8 waves x [16][68] bf16, 17408 B
  uint32_t* mb = (uint32_t*)smem;              // merge buf [128][36] (reuses As/Bs)

  const int t = threadIdx.x;
  const int l = t & 63;
  const int wid = t >> 6;
  const int wm = wid >> 2;       // 0..1
  const int wn = wid & 3;        // 0..3
  const int g = l >> 4;          // k-chunk / row-quad group
  const int m = l & 15;
  const long rb = (long)blockIdx.x * 128;

  const int ar = t >> 2, ac = t & 3;           // staging coords (row, k-chunk)
  const uint4* Agp = (const uint4*)An + (rb + ar) * 64 + ac;  // row stride 64 uint4
  const uint4* Bgp = (const uint4*)Bn;

  int aIdx[4], bIdx[8];
#pragma unroll
  for (int fm = 0; fm < 4; ++fm) aIdx[fm] = g * 128 + wm * 64 + fm * 16 + m;
#pragma unroll
  for (int fn = 0; fn < 8; ++fn) bIdx[fn] = g * 512 + wn * 128 + fn * 16 + m;

  uint32_t t8[4][8];
#pragma unroll
  for (int a = 0; a < 4; ++a)
#pragma unroll
    for (int i = 0; i < 8; ++i) t8[a][i] = 0u;

  // initial prefetch (ni=0, kt=0)
  uint4 pa = Agp[0];
  uint4 pb0 = Bgp[(0 + ar) * 64 + ac];
  uint4 pb1 = Bgp[(128 + ar) * 64 + ac];
  uint4 pb2 = Bgp[(256 + ar) * 64 + ac];
  uint4 pb3 = Bgp[(384 + ar) * 64 + ac];

  for (int ni = 0; ni < 8; ++ni) {
    const int n0 = ni * 512;
    f32x4 acc[4][8];
#pragma unroll
    for (int fm = 0; fm < 4; ++fm)
#pragma unroll
      for (int fn = 0; fn < 8; ++fn) acc[fm][fn] = (f32x4){0.f, 0.f, 0.f, 0.f};

    for (int kt = 0; kt < 16; ++kt) {
      __syncthreads();                          // prev compute done reading LDS
      As[ac * 128 + ar] = pa;
      Bs[ac * 512 + ar] = pb0;
      Bs[ac * 512 + 128 + ar] = pb1;
      Bs[ac * 512 + 256 + ar] = pb2;
      Bs[ac * 512 + 384 + ar] = pb3;
      { // prefetch next k-tile (wraps harmlessly at the very end)
        int nkt = kt + 1, nni = ni;
        if (nkt == 16) { nkt = 0; ++nni; if (nni == 8) nni = 0; }
        pa = Agp[nkt * 4];
        const long bb = ((long)nni * 512 + ar) * 64 + nkt * 4 + ac;
        pb0 = Bgp[bb];
        pb1 = Bgp[bb + 128 * 64];
        pb2 = Bgp[bb + 256 * 64];
        pb3 = Bgp[bb + 384 * 64];
      }
      __syncthreads();                          // staged tile visible
      uint4 a4[4];
#pragma unroll
      for (int fm = 0; fm < 4; ++fm) a4[fm] = As[aIdx[fm]];
#pragma unroll
      for (int h = 0; h < 2; ++h) {
        uint4 b4[4];
#pragma unroll
        for (int i = 0; i < 4; ++i) b4[i] = Bs[bIdx[4 * h + i]];
#pragma unroll
        for (int fm = 0; fm < 4; ++fm)
#pragma unroll
          for (int i = 0; i < 4; ++i)
            acc[fm][4 * h + i] = __builtin_amdgcn_mfma_f32_16x16x32_bf16(
                __builtin_bit_cast(s16x8, a4[fm]),
                __builtin_bit_cast(s16x8, b4[i]),
                acc[fm][4 * h + i], 0, 0, 0);
      }
    }

    // dump + scan (wave-private LDS region; DS ops in-order per wave)
#pragma unroll
    for (int fm = 0; fm < 4; ++fm) {
#pragma unroll
      for (int h = 0; h < 2; ++h) {
#pragma unroll
        for (int fi = 0; fi < 4; ++fi)
#pragma unroll
          for (int r = 0; r < 4; ++r)
            dmp[(wid * 16 + 4 * g + r) * 68 + 16 * fi + m] = f2bf(acc[fm][4 * h + fi][r]);
        asm volatile("s_waitcnt lgkmcnt(0)" ::: "memory");
        const int colb = n0 + wn * 128 + h * 64 + g * 16;
#pragma unroll
        for (int j = 0; j < 4; ++j) {
          const uint2 v = *(const uint2*)(dmp + (wid * 16 + m) * 68 + g * 16 + 4 * j);
          const uint32_t k0 = (mapbf(v.x & 0xFFFFu) << 16) | (uint32_t)(colb + 4 * j + 0);
          const uint32_t k1 = (mapbf(v.x >> 16)     << 16) | (uint32_t)(colb + 4 * j + 1);
          const uint32_t k2 = (mapbf(v.y & 0xFFFFu) << 16) | (uint32_t)(colb + 4 * j + 2);
          const uint32_t k3 = (mapbf(v.y >> 16)     << 16) | (uint32_t)(colb + 4 * j + 3);
          const uint32_t mx = umx(umx(k0, k1), umx(k2, k3));
          if (mx > t8[fm][7]) {
            ins8(t8[fm], k0); ins8(t8[fm], k1); ins8(t8[fm], k2); ins8(t8[fm], k3);
          }
        }
      }
    }
  }

  __syncthreads();
  // per-row merge across the 4 col-quarters (lanes l, l^16, l^32, l^48)
#pragma unroll
  for (int fm = 0; fm < 4; ++fm) {
    uint32_t cur[8];
#pragma unroll
    for (int i = 0; i < 8; ++i) cur[i] = t8[fm][i];
    mergeshfl(cur, 16);
    mergeshfl(cur, 32);
    if (l < 16) {
      const int row = wm * 64 + fm * 16 + m;
      uint32_t* dst = mb + row * 36 + wn * 8;
      uint4 u0; u0.x = cur[0]; u0.y = cur[1]; u0.z = cur[2]; u0.w = cur[3];
      uint4 u1; u1.x = cur[4]; u1.y = cur[5]; u1.z = cur[6]; u1.w = cur[7];
      *(uint4*)(dst) = u0;
      *(uint4*)(dst + 4) = u1;
    }
  }
  __syncthreads();
  if (t < 128) {
    const int row = t;
    const uint32_t* src = mb + row * 36;
    uint32_t A8[8], B8[8], C8[8], D8[8];
#pragma unroll
    for (int i = 0; i < 8; ++i) { A8[i] = src[i]; B8[i] = src[8 + i]; C8[i] = src[16 + i]; D8[i] = src[24 + i]; }
    bmerge(A8, B8); bmerge(C8, D8); bmerge(A8, C8);
    int* outp = top8out + (rb + row) * 8;
#pragma unroll
    for (int i = 0; i < 8; ++i) outp[i] = (int)(A8[i] & 0xFFFu);
  }
}

// ---------------------------------------------------------------------------
// finalize: one wave per row. fp64 rescore of 8 candidates, top-3 (tie ->
// lower proto index), softmax(x5), MLP via rproj/cproj, weighted sum.
// ---------------------------------------------------------------------------
__global__ __launch_bounds__(256) void finalize_kernel(
    const float* __restrict__ regime, const float* __restrict__ protoNf,
    const int* __restrict__ top8, const float* __restrict__ nrm_r,
    const float* __restrict__ rproj, const float* __restrict__ cproj,
    const float* __restrict__ b1, const float* __restrict__ W2,
    const float* __restrict__ b2, float* __restrict__ out)
{
  __shared__ float rlds[4][512];
  const int t = threadIdx.x, l = t & 63, w = t >> 6;
  const long b = (long)blockIdx.x * 4 + w;

  { // stage fp32-normalized regime row (divide to match reference elementwise)
    const float n = nrm_r[b];
    const float4* gp = (const float4*)(regime + b * BDIM);
    float4 v0 = gp[l], v1 = gp[64 + l];
    v0.x /= n; v0.y /= n; v0.z /= n; v0.w /= n;
    v1.x /= n; v1.y /= n; v1.z /= n; v1.w /= n;
    *(float4*)&rlds[w][4 * l] = v0;
    *(float4*)&rlds[w][256 + 4 * l] = v1;
  }
  __syncthreads();

  const int j = l >> 3;                        // 8 lanes per candidate
  const int pj = top8[b * 8 + j];
  double dd = 0.0;
  {
    const float4* pp = (const float4*)(protoNf + (long)pj * BDIM);
    const float4* rr = (const float4*)&rlds[w][0];
#pragma unroll
    for (int u = 0; u < 16; ++u) {
      const float4 p4 = pp[(l & 7) + 8 * u];
      const float4 r4 = rr[(l & 7) + 8 * u];  // same-address broadcast across groups
      dd = fma((double)p4.x, (double)r4.x, dd);
      dd = fma((double)p4.y, (double)r4.y, dd);
      dd = fma((double)p4.z, (double)r4.z, dd);
      dd = fma((double)p4.w, (double)r4.w, dd);
    }
  }
  dd += __shfl_xor(dd, 1, 64);
  dd += __shfl_xor(dd, 2, 64);
  dd += __shfl_xor(dd, 4, 64);

  double sall[8]; int pall[8];
#pragma unroll
  for (int q = 0; q < 8; ++q) {
    sall[q] = __shfl(dd, q * 8, 64);
    pall[q] = __shfl(pj, q * 8, 64);
  }
  // top-3, tie -> lower prototype index (all lanes redundantly)
  double vv[3]; int ppi[3]; unsigned chosen = 0;
#pragma unroll
  for (int r = 0; r < 3; ++r) {
    double bv = -1e300; int bp = 0x7FFFFFFF; int bq = 0;
#pragma unroll
    for (int q = 0; q < 8; ++q) {
      const bool ex = (chosen >> q) & 1u;
      const bool better = !ex && ((sall[q] > bv) || (sall[q] == bv && pall[q] < bp));
      bv = better ? sall[q] : bv;
      bp = better ? pall[q] : bp;
      bq = better ? q : bq;
    }
    vv[r] = bv; ppi[r] = bp; chosen |= 1u << bq;
  }
  const float v0f = (float)vv[0], v1f = (float)vv[1], v2f = (float)vv[2];
  const float e1 = expf(5.f * (v1f - v0f));
  const float e2 = expf(5.f * (v2f - v0f));
  const float winv = 1.f / (1.f + e1 + e2);
  const float w0 = winv, w1 = e1 * winv, w2 = e2 * winv;

  // MLP: h = relu(rproj + cproj[p] + b1); feats = W2 @ h; out = sum wk*feats + b2
  const int hu = l & 31, o = l & 15;
  const float rpv = rproj[b * 32 + hu];
  const float b1v = b1[hu];
  float w2row[32];
#pragma unroll
  for (int hh = 0; hh < 32; ++hh) w2row[hh] = W2[o * 32 + hh];
  float outacc = (l < 16) ? b2[o] : 0.f;       // sum(w)=1 so b2 added once
#pragma unroll
  for (int k = 0; k < 3; ++k) {
    const float cpv = cproj[(long)ppi[k] * 32 + hu];
    const float hval = fmaxf(rpv + cpv + b1v, 0.f);
    float f = 0.f;
#pragma unroll
    for (int hh = 0; hh < 32; ++hh) f = fmaf(w2row[hh], __shfl(hval, hh, 64), f);
    const float wk = (k == 0) ? w0 : ((k == 1) ? w1 : w2);
    outacc = fmaf(wk, f, outacc);
  }
  if (l < 16) out[b * 16 + o] = outacc;
}

// ---------------------------------------------------------------------------
extern "C" void kernel_launch(void* const* d_in, const int* in_sizes, int n_in,
                              void* d_out, int out_size, void* d_ws, size_t ws_size,
                              hipStream_t stream)
{
  (void)in_sizes; (void)n_in; (void)out_size; (void)ws_size;
  const float* regime = (const float*)d_in[0];
  const float* protos = (const float*)d_in[1];
  const float* W1     = (const float*)d_in[2];
  const float* b1     = (const float*)d_in[3];
  const float* W2     = (const float*)d_in[4];
  const float* b2     = (const float*)d_in[5];
  float* out = (float*)d_out;

  // workspace carve (~50 MB)
  char* ws = (char*)d_ws;
  u16*   protoN  = (u16*)ws;    ws += (size_t)NP * BDIM * 2;       //  4 MB
  u16*   regimeN = (u16*)ws;    ws += (size_t)NB * BDIM * 2;       // 32 MB
  float* nrm_p   = (float*)ws;  ws += (size_t)NP * 4;
  float* nrm_r   = (float*)ws;  ws += (size_t)NB * 4;
  float* cproj   = (float*)ws;  ws += (size_t)NP * 32 * 4;
  float* rproj   = (float*)ws;  ws += (size_t)NB * 32 * 4;         //  4 MB
  int*   top8    = (int*)ws;    ws += (size_t)NB * 8 * 4;          //  1 MB
  float* protoNf = (float*)ws;  /* NP*BDIM*4 = 8 MB */

  hipLaunchKernelGGL(prep_kernel, dim3(NP / 16), dim3(256), 0, stream,
                     protos, W1, 512, protoN, nrm_p, cproj, protoNf);
  hipLaunchKernelGGL(prep_kernel, dim3(NB / 16), dim3(256), 0, stream,
                     regime, W1, 0, regimeN, nrm_r, rproj, (float*)nullptr);
  hipLaunchKernelGGL(topk_kernel, dim3(NB / 128), dim3(512), 0, stream,
                     regimeN, protoN, top8);
  hipLaunchKernelGGL(finalize_kernel, dim3(NB / 4), dim3(256), 0, stream,
                     regime, protoNf, top8, nrm_r, rproj, cproj, b1, W2, b2, out);
}

// Round 3
// 425.551 us; speedup vs baseline: 1.1290x; 1.1290x over previous
//
#include <hip/hip_runtime.h>
#include <stdint.h>

// RegimePatternBank: B=32768 regime rows (D=512), P=4096 prototypes.
//  prep (x2): norms, bf16-normalized rows (regime: row-major; proto: K-chunked
//             layout for coalesced global_load_lds staging), fp32-normalized
//             protos, MLP projections rproj/cproj (layer-1 is linear in concat,
//             W1 held in registers, 16 rows/block, 2 barriers).
//  topk:      bf16 MFMA GEMM with SWAPPED operands (proto=A, regime=B) so each
//             lane owns whole sim rows -> in-register top-3/lane (packed
//             f32key|col), merged 4 g-lanes x 2 proto-half-waves -> top-8/row.
//             512 blocks (2/CU), global_load_lds staging, dbuf LDS, raw
//             s_barrier + vmcnt(0) per K=64 phase, XOR-swizzled LDS reads with
//             inverse-swizzled global sources.
//  finalize:  fp64 rescore of all 8 candidates, exact top-3 (tie -> lower
//             index), softmax(x5), fused MLP via rproj/cproj.

#define BDIM 512
#define NB   32768
#define NP   4096
#define PCH  256    // protos per ni chunk in topk

typedef float  f32x4 __attribute__((ext_vector_type(4)));
typedef short  s16x8 __attribute__((ext_vector_type(8)));
typedef unsigned short u16;

typedef const __attribute__((address_space(1))) unsigned int* gas_t;
typedef __attribute__((address_space(3))) unsigned int* las_t;

__device__ __forceinline__ void gll16(const void* g, void* l) {
  __builtin_amdgcn_global_load_lds((gas_t)g, (las_t)l, 16, 0, 0);
}

__device__ __forceinline__ u16 f2bf(float f) {
  uint32_t u = __float_as_uint(f);
  return (u16)((u + 0x7FFFu + ((u >> 16) & 1u)) >> 16);
}
__device__ __forceinline__ uint32_t umx(uint32_t a, uint32_t b) { return a > b ? a : b; }
__device__ __forceinline__ uint32_t umn(uint32_t a, uint32_t b) { return a > b ? b : a; }

// map f32 bits -> u32 with float ordering; pack top-20 value bits | 12-bit col
__device__ __forceinline__ uint32_t packkey(float v, int col) {
  uint32_t u = __float_as_uint(v);
  uint32_t mp = u ^ (uint32_t)(((int)u >> 31) | 0x80000000);
  return (mp & 0xFFFFF000u) | (uint32_t)col;
}
__device__ __forceinline__ float unpackf(uint32_t k) {
  uint32_t mbits = k & 0xFFFFF000u;
  uint32_t u = (mbits & 0x80000000u) ? (mbits ^ 0x80000000u) : ~mbits;
  return __uint_as_float(u);
}

// a,b sorted desc -> a = top-8 of union (bitonic merge network)
__device__ __forceinline__ void bmerge(uint32_t* a, const uint32_t* b) {
  uint32_t t[8];
#pragma unroll
  for (int i = 0; i < 8; ++i) t[i] = umx(a[i], b[7 - i]);
#pragma unroll
  for (int i = 0; i < 4; ++i) { uint32_t x = umx(t[i], t[i + 4]), y = umn(t[i], t[i + 4]); t[i] = x; t[i + 4] = y; }
#pragma unroll
  for (int g = 0; g < 8; g += 4)
#pragma unroll
    for (int i = 0; i < 2; ++i) { uint32_t x = umx(t[g + i], t[g + i + 2]), y = umn(t[g + i], t[g + i + 2]); t[g + i] = x; t[g + i + 2] = y; }
#pragma unroll
  for (int p = 0; p < 8; p += 2) { uint32_t x = umx(t[p], t[p + 1]), y = umn(t[p], t[p + 1]); t[p] = x; t[p + 1] = y; }
#pragma unroll
  for (int i = 0; i < 8; ++i) a[i] = t[i];
}
__device__ __forceinline__ void mergeshfl(uint32_t* a, int mask) {
  uint32_t b[8];
#pragma unroll
  for (int i = 0; i < 8; ++i) b[i] = (uint32_t)__shfl_xor((int)a[i], mask, 64);
  bmerge(a, b);
}

// ---------------------------------------------------------------------------
// prep: 16 rows/block, 256 thr. W1-half in registers (64/thread). mode 0 =
// regime (row-major bf16 + nrm), mode 1 = proto (K-chunked bf16 [8][NP][128B]
// + fp32 normalized). Both: proj = W1[:, w1_off:+512] @ raw_row.
// ---------------------------------------------------------------------------
__global__ __launch_bounds__(256) void prep_kernel(
    const float* __restrict__ src, const float* __restrict__ W1, int w1_off,
    int mode, u16* __restrict__ obf, float* __restrict__ onrm,
    float* __restrict__ oproj, float* __restrict__ onf32)
{
  __shared__ float rows[16][512];     // 32 KB
  __shared__ float pscr[16][8][32];   // 16 KB
  const int t = threadIdx.x, l = t & 63, w = t >> 6;
  const long rowbase = (long)blockIdx.x * 16;

  { // stage 16 raw rows: thread t -> row t>>4, cols (t&15)*32..+32
    const int r = t >> 4, c0 = (t & 15) * 32;
    const float4* gp = (const float4*)(src + (rowbase + r) * BDIM + c0);
    float4* dp = (float4*)&rows[r][c0];
#pragma unroll
    for (int i = 0; i < 8; ++i) dp[i] = gp[i];
  }
  float wreg[64]; // thread (h=t&31, seg=t>>5) holds W1[h][w1_off+seg*64 .. +64)
  {
    const int h = t & 31, seg = t >> 5;
    const float* wp = W1 + h * 1024 + w1_off + seg * 64;
#pragma unroll
    for (int i = 0; i < 64; ++i) wreg[i] = wp[i];
  }
  __syncthreads();

  // normalize: wave w handles rows 4w..4w+3
#pragma unroll
  for (int i = 0; i < 4; ++i) {
    const int r = w * 4 + i;
    const long row = rowbase + r;
    float4 a = *(const float4*)&rows[r][4 * l];
    float4 c = *(const float4*)&rows[r][256 + 4 * l];
    float ss = a.x * a.x + a.y * a.y + a.z * a.z + a.w * a.w
             + c.x * c.x + c.y * c.y + c.z * c.z + c.w * c.w;
#pragma unroll
    for (int msk = 1; msk < 64; msk <<= 1) ss += __shfl_xor(ss, msk, 64);
    const float n = fmaxf(sqrtf(ss), 1e-12f);
    float4 qa, qc;
    qa.x = a.x / n; qa.y = a.y / n; qa.z = a.z / n; qa.w = a.w / n;
    qc.x = c.x / n; qc.y = c.y / n; qc.z = c.z / n; qc.w = c.w / n;
    ushort4 u0, u1;
    u0.x = f2bf(qa.x); u0.y = f2bf(qa.y); u0.z = f2bf(qa.z); u0.w = f2bf(qa.w);
    u1.x = f2bf(qc.x); u1.y = f2bf(qc.y); u1.z = f2bf(qc.z); u1.w = f2bf(qc.w);
    if (mode == 0) {
      if (l == 0) onrm[row] = n;
      *(ushort4*)(obf + row * BDIM + 4 * l) = u0;
      *(ushort4*)(obf + row * BDIM + 256 + 4 * l) = u1;
    } else {
      // protoK[kp][proto][64 bf16]: a covers k=4l..4l+3 (kp=l>>4),
      // c covers k=256+4l..+3 (kp=4+(l>>4)); byte-in-chunk = 8*(l&15)
      char* base = (char*)obf;
      *(ushort4*)(base + ((long)(l >> 4) * NP + row) * 128 + 8 * (l & 15)) = u0;
      *(ushort4*)(base + ((long)(4 + (l >> 4)) * NP + row) * 128 + 8 * (l & 15)) = u1;
      *(float4*)(onf32 + row * BDIM + 4 * l) = qa;
      *(float4*)(onf32 + row * BDIM + 256 + 4 * l) = qc;
    }
  }

  // proj partials on RAW rows (no barrier inside the loop)
  const int h = t & 31, seg = t >> 5;
  for (int r = 0; r < 16; ++r) {
    float p = 0.f;
#pragma unroll
    for (int j = 0; j < 16; ++j) {
      const float4 rv = *(const float4*)&rows[r][seg * 64 + 4 * j];
      p = fmaf(wreg[4 * j + 0], rv.x, p);
      p = fmaf(wreg[4 * j + 1], rv.y, p);
      p = fmaf(wreg[4 * j + 2], rv.z, p);
      p = fmaf(wreg[4 * j + 3], rv.w, p);
    }
    pscr[r][seg][h] = p;
  }
  __syncthreads();
  // reduce: 512 outputs (16 rows x 32 h), 2 per thread
#pragma unroll
  for (int q = 0; q < 2; ++q) {
    const int idx = t + q * 256;
    const int rr = idx >> 5, hh = idx & 31;
    float s = 0.f;
#pragma unroll
    for (int sg = 0; sg < 8; ++sg) s += pscr[rr][sg][hh];
    oproj[(rowbase + rr) * 32 + hh] = s;
  }
}

// ---------------------------------------------------------------------------
// topk: 512 blocks x 256 thr (4 waves). Block: 64 regime rows x full P sweep
// (16 ni-chunks of 256 protos). Wave tile: 128 protos x 32 regimes
// (8 m-frags x 2 n-frags of 16x16x32 bf16, swapped operands). K staged in
// 64-wide phases via global_load_lds, double-buffered (80 KB LDS).
// ---------------------------------------------------------------------------
__global__ __launch_bounds__(256, 2) void topk_kernel(
    const u16* __restrict__ Rn,   // [32768][512] bf16 (row-major)
    const u16* __restrict__ Pk,   // [8][4096][64] bf16 (K-chunked)
    uint32_t* __restrict__ keys8) // [32768][8] packed keys
{
  __shared__ uint4 lds4[5120];    // 81920 B: 2 bufs x (32KB proto + 8KB regime)
  char* ldsb = (char*)lds4;

  const int t = threadIdx.x, l = t & 63, wid = t >> 6;
  const int wp = wid >> 1;        // proto half (0..1)
  const int wr = wid & 1;         // regime half (0..1)
  const int g = l >> 4, m = l & 15;
  const long rb = (long)blockIdx.x * 64;
  const char* Pkb = (const char*)Pk;
  const char* Rnb = (const char*)Rn;
  const int swsrc = 16 * ((l & 7) ^ ((l >> 3) & 7));  // inverse-swizzled source
  const int lrow8 = (l >> 3);

  f32x4 acc[8][2];
  uint32_t k3[2][3];
  float thr[2];
#pragma unroll
  for (int fn = 0; fn < 2; ++fn) {
    thr[fn] = -1e30f;
#pragma unroll
    for (int i = 0; i < 3; ++i) k3[fn][i] = 0u;
  }

#define ISSUE(buf, ni_, kp_)                                                   \
  do {                                                                         \
    char* lp_ = ldsb + (buf) * 40960;                                          \
    const char* pg = Pkb + ((long)(kp_) * NP + (ni_) * PCH) * 128;             \
    _Pragma("unroll")                                                          \
    for (int i_ = 0; i_ < 8; ++i_) {                                           \
      const int ch_ = wid * 8 + i_;                                            \
      gll16(pg + ch_ * 1024 + lrow8 * 128 + swsrc, lp_ + ch_ * 1024);          \
    }                                                                          \
    _Pragma("unroll")                                                          \
    for (int j_ = 0; j_ < 2; ++j_) {                                           \
      const int ch_ = wid * 2 + j_;                                            \
      gll16(Rnb + (rb + ch_ * 8 + lrow8) * 1024 + (kp_) * 128 + swsrc,         \
            lp_ + 32768 + ch_ * 1024);                                         \
    }                                                                          \
  } while (0)

  ISSUE(0, 0, 0);

  for (int ni = 0; ni < 16; ++ni) {
#pragma unroll
    for (int fm = 0; fm < 8; ++fm)
#pragma unroll
      for (int fn = 0; fn < 2; ++fn) acc[fm][fn] = (f32x4){0.f, 0.f, 0.f, 0.f};

    for (int kp = 0; kp < 8; ++kp) {
      const int ph = ni * 8 + kp;
      asm volatile("s_waitcnt vmcnt(0)" ::: "memory");
      __builtin_amdgcn_s_barrier();
      const int nph = ph + 1;
      if (nph < 128) ISSUE(nph & 1, nph >> 3, nph & 7);
      __builtin_amdgcn_sched_barrier(0);
      const char* lp = ldsb + (ph & 1) * 40960;
      const char* lr = lp + 32768;
      const int sw = 16 * (m & 7);
#pragma unroll
      for (int ks = 0; ks < 2; ++ks) {
        const int koff = (ks * 64 + 16 * g) ^ sw;
        const char* pbr = lr + (wr * 32 + m) * 128 + koff;
        const char* pa = lp + (wp * 128 + m) * 128 + koff;
        uint4 b0 = *(const uint4*)(pbr);
        uint4 b1 = *(const uint4*)(pbr + 2048);
#pragma unroll
        for (int fm = 0; fm < 8; ++fm) {
          uint4 a4 = *(const uint4*)(pa + fm * 2048);
          acc[fm][0] = __builtin_amdgcn_mfma_f32_16x16x32_bf16(
              __builtin_bit_cast(s16x8, a4), __builtin_bit_cast(s16x8, b0),
              acc[fm][0], 0, 0, 0);
          acc[fm][1] = __builtin_amdgcn_mfma_f32_16x16x32_bf16(
              __builtin_bit_cast(s16x8, a4), __builtin_bit_cast(s16x8, b1),
              acc[fm][1], 0, 0, 0);
        }
      }
    }

    // in-register selection: lane owns sim rows (regime wr*32+fn*16+m);
    // protos this ni: pb0 + fm*16 + r  (C/D: col=lane&15, row=4*(l>>4)+reg)
    const int pb0 = ni * PCH + wp * 128 + 4 * g;
#pragma unroll
    for (int fn = 0; fn < 2; ++fn) {
#pragma unroll
      for (int fm = 0; fm < 8; ++fm) {
        const f32x4 v = acc[fm][fn];
        const float m4 = fmaxf(fmaxf(v[0], v[1]), fmaxf(v[2], v[3]));
        if (m4 > thr[fn]) {
#pragma unroll
          for (int r = 0; r < 4; ++r) {
            uint32_t kk = packkey(v[r], pb0 + fm * 16 + r);
            uint32_t mx0 = umx(k3[fn][0], kk), mn0 = umn(k3[fn][0], kk);
            k3[fn][0] = mx0; kk = mn0;
            uint32_t mx1 = umx(k3[fn][1], kk), mn1 = umn(k3[fn][1], kk);
            k3[fn][1] = mx1; kk = mn1;
            k3[fn][2] = umx(k3[fn][2], kk);
          }
          thr[fn] = unpackf(k3[fn][2]);
        }
      }
    }
  }
#undef ISSUE

  // merge: 4 g-lanes per row, then the two wp halves via LDS
  uint32_t* mrg = (uint32_t*)ldsb;   // [64 rows][8]
  uint32_t cur[2][8];
#pragma unroll
  for (int fn = 0; fn < 2; ++fn) {
    cur[fn][0] = k3[fn][0]; cur[fn][1] = k3[fn][1]; cur[fn][2] = k3[fn][2];
#pragma unroll
    for (int i = 3; i < 8; ++i) cur[fn][i] = 0u;
    mergeshfl(cur[fn], 16);
    mergeshfl(cur[fn], 32);
  }
  __syncthreads();   // all phases drained; bufs free for reuse
#pragma unroll
  for (int fn = 0; fn < 2; ++fn)
    if (wp == 1 && g == fn) {
      uint32_t* d = mrg + (wr * 32 + fn * 16 + m) * 8;
      uint4 a; a.x = cur[fn][0]; a.y = cur[fn][1]; a.z = cur[fn][2]; a.w = cur[fn][3];
      uint4 b; b.x = cur[fn][4]; b.y = cur[fn][5]; b.z = cur[fn][6]; b.w = cur[fn][7];
      *(uint4*)(d) = a; *(uint4*)(d + 4) = b;
    }
  __syncthreads();
#pragma unroll
  for (int fn = 0; fn < 2; ++fn)
    if (wp == 0 && g == fn) {
      const int row = wr * 32 + fn * 16 + m;
      uint32_t oth[8];
#pragma unroll
      for (int i = 0; i < 8; ++i) oth[i] = mrg[row * 8 + i];
      bmerge(cur[fn], oth);
      uint32_t* d = keys8 + (rb + row) * 8;
      uint4 a; a.x = cur[fn][0]; a.y = cur[fn][1]; a.z = cur[fn][2]; a.w = cur[fn][3];
      uint4 b; b.x = cur[fn][4]; b.y = cur[fn][5]; b.z = cur[fn][6]; b.w = cur[fn][7];
      *(uint4*)(d) = a; *(uint4*)(d + 4) = b;
    }
}

// ---------------------------------------------------------------------------
// finalize: one wave per row. fp64 rescore of all 8 candidates, exact top-3
// (tie -> lower index), softmax(x5), MLP via rproj/cproj, weighted sum.
// ---------------------------------------------------------------------------
__global__ __launch_bounds__(256) void finalize_kernel(
    const float* __restrict__ regime, const float* __restrict__ protoNf,
    const uint32_t* __restrict__ keys8, const float* __restrict__ nrm_r,
    const float* __restrict__ rproj, const float* __restrict__ cproj,
    const float* __restrict__ b1, const float* __restrict__ W2,
    const float* __restrict__ b2, float* __restrict__ out)
{
  __shared__ float rlds[4][512];
  const int t = threadIdx.x, l = t & 63, w = t >> 6;
  const long b = (long)blockIdx.x * 4 + w;

  { // stage fp32-normalized regime row
    const float n = nrm_r[b];
    const float4* gp = (const float4*)(regime + b * BDIM);
    float4 v0 = gp[l], v1 = gp[64 + l];
    v0.x /= n; v0.y /= n; v0.z /= n; v0.w /= n;
    v1.x /= n; v1.y /= n; v1.z /= n; v1.w /= n;
    *(float4*)&rlds[w][4 * l] = v0;
    *(float4*)&rlds[w][256 + 4 * l] = v1;
  }
  __syncthreads();

  const int j = l >> 3;                         // 8 lanes per candidate
  const uint32_t key = keys8[b * 8 + j];
  const int pj = (int)(key & 0xFFFu);

  double dd = 0.0;
  {
    const float4* pp = (const float4*)(protoNf + (long)pj * BDIM);
    const float4* rr = (const float4*)&rlds[w][0];
#pragma unroll
    for (int u = 0; u < 16; ++u) {
      const float4 p4 = pp[(l & 7) + 8 * u];
      const float4 r4 = rr[(l & 7) + 8 * u];
      dd = fma((double)p4.x, (double)r4.x, dd);
      dd = fma((double)p4.y, (double)r4.y, dd);
      dd = fma((double)p4.z, (double)r4.z, dd);
      dd = fma((double)p4.w, (double)r4.w, dd);
    }
  }
  dd += __shfl_xor(dd, 1, 64);
  dd += __shfl_xor(dd, 2, 64);
  dd += __shfl_xor(dd, 4, 64);

  double sall[8]; int pall[8];
#pragma unroll
  for (int q = 0; q < 8; ++q) {
    sall[q] = __shfl(dd, q * 8, 64);
    pall[q] = __shfl(pj, q * 8, 64);
  }
  // top-3, tie -> lower prototype index
  double vv[3]; int ppi[3]; unsigned chosen = 0;
#pragma unroll
  for (int r = 0; r < 3; ++r) {
    double bv = -1e301; int bp = 0x7FFFFFFF; int bq = 0;
#pragma unroll
    for (int q = 0; q < 8; ++q) {
      const bool ex = (chosen >> q) & 1u;
      const bool better = !ex && ((sall[q] > bv) || (sall[q] == bv && pall[q] < bp));
      bv = better ? sall[q] : bv;
      bp = better ? pall[q] : bp;
      bq = better ? q : bq;
    }
    vv[r] = bv; ppi[r] = bp; chosen |= 1u << bq;
  }
  const float v0f = (float)vv[0], v1f = (float)vv[1], v2f = (float)vv[2];
  const float e1 = expf(5.f * (v1f - v0f));
  const float e2 = expf(5.f * (v2f - v0f));
  const float winv = 1.f / (1.f + e1 + e2);
  const float w0 = winv, w1 = e1 * winv, w2 = e2 * winv;

  // MLP: h = relu(rproj + cproj[p] + b1); feats = W2 @ h; out = sum wk*feats + b2
  const int hu = l & 31, o = l & 15;
  const float rpv = rproj[b * 32 + hu];
  const float b1v = b1[hu];
  float w2row[32];
#pragma unroll
  for (int hh = 0; hh < 32; ++hh) w2row[hh] = W2[o * 32 + hh];
  float outacc = (l < 16) ? b2[o] : 0.f;        // sum(w)=1 so b2 added once
#pragma unroll
  for (int k = 0; k < 3; ++k) {
    const float cpv = cproj[(long)ppi[k] * 32 + hu];
    const float hval = fmaxf(rpv + cpv + b1v, 0.f);
    float f = 0.f;
#pragma unroll
    for (int hh = 0; hh < 32; ++hh) f = fmaf(w2row[hh], __shfl(hval, hh, 64), f);
    const float wk = (k == 0) ? w0 : ((k == 1) ? w1 : w2);
    outacc = fmaf(wk, f, outacc);
  }
  if (l < 16) out[b * 16 + o] = outacc;
}

// ---------------------------------------------------------------------------
extern "C" void kernel_launch(void* const* d_in, const int* in_sizes, int n_in,
                              void* d_out, int out_size, void* d_ws, size_t ws_size,
                              hipStream_t stream)
{
  (void)in_sizes; (void)n_in; (void)out_size; (void)ws_size;
  const float* regime = (const float*)d_in[0];
  const float* protos = (const float*)d_in[1];
  const float* W1     = (const float*)d_in[2];
  const float* b1     = (const float*)d_in[3];
  const float* W2     = (const float*)d_in[4];
  const float* b2     = (const float*)d_in[5];
  float* out = (float*)d_out;

  char* ws = (char*)d_ws;
  u16*      protoK  = (u16*)ws;      ws += (size_t)NP * BDIM * 2;   //  4 MB
  u16*      regimeN = (u16*)ws;      ws += (size_t)NB * BDIM * 2;   // 32 MB
  float*    protoNf = (float*)ws;    ws += (size_t)NP * BDIM * 4;   //  8 MB
  float*    nrm_r   = (float*)ws;    ws += (size_t)NB * 4;
  float*    cproj   = (float*)ws;    ws += (size_t)NP * 32 * 4;
  float*    rproj   = (float*)ws;    ws += (size_t)NB * 32 * 4;     //  4 MB
  uint32_t* keys8   = (uint32_t*)ws; ws += (size_t)NB * 8 * 4;      //  1 MB

  hipLaunchKernelGGL(prep_kernel, dim3(NP / 16), dim3(256), 0, stream,
                     protos, W1, 512, 1, protoK, (float*)nullptr, cproj, protoNf);
  hipLaunchKernelGGL(prep_kernel, dim3(NB / 16), dim3(256), 0, stream,
                     regime, W1, 0, 0, regimeN, nrm_r, rproj, (float*)nullptr);
  hipLaunchKernelGGL(topk_kernel, dim3(512), dim3(256), 0, stream,
                     regimeN, protoK, keys8);
  hipLaunchKernelGGL(finalize_kernel, dim3(NB / 4), dim3(256), 0, stream,
                     regime, protoNf, keys8, nrm_r, rproj, cproj, b1, W2, b2, out);
}